// Round 16
// baseline (90.522 us; speedup 1.0000x reference)
//
#include <hip/hip_runtime.h>

typedef _Float16 h16;
typedef _Float16 f16x8 __attribute__((ext_vector_type(8)));
typedef _Float16 f16x4 __attribute__((ext_vector_type(4)));
typedef float f32x4 __attribute__((ext_vector_type(4)));

#define KSCALE_FOLD 11.541560327111707f   // 8 * log2(e), folded into Kh

#if __has_builtin(__builtin_amdgcn_exp2f)
#define EXP2(x) __builtin_amdgcn_exp2f(x)
#else
static __device__ __forceinline__ float EXP2(float x) {
    float r; asm("v_exp_f32 %0, %1" : "=v"(r) : "v"(x)); return r;
}
#endif

// ---------------- fused pre-pass: weight transposes + x stats/convert + null kv ----------------
__global__ __launch_bounds__(256) void pre_k(const float* __restrict__ Wq,
    const float* __restrict__ Wkv, const float* __restrict__ Wout,
    const float* __restrict__ gamma, const float* __restrict__ x,
    const float* __restrict__ nkv, const float* __restrict__ kscale,
    h16* __restrict__ W1t, h16* __restrict__ Wot, float* __restrict__ cqp,
    float* __restrict__ mu, float* __restrict__ rr, h16* __restrict__ xh,
    h16* __restrict__ Kh, h16* __restrict__ Vth)
{
    __shared__ float ts[64][65];
    int pid = blockIdx.x;
    int tid = threadIdx.x;
    if (pid < 544) {
        int bx = pid & 15, by = pid >> 4;
        int c = tid & 63, rc = tid >> 6;
        const float* src; int ld, scol, drow0; h16* dst; bool useg = false;
        if (by < 16)      { src = Wq;   ld = 1024; scol = by*64;       dst = W1t; drow0 = scol;        useg = true; }
        else if (by < 18) { src = Wkv;  ld = 128;  scol = (by-16)*64;  dst = W1t; drow0 = 1024 + scol; }
        else              { src = Wout; ld = 1024; scol = (by-18)*64;  dst = Wot; drow0 = scol; }
        float part = 0.f;
#pragma unroll
        for (int i = 0; i < 16; ++i) {
            int r = rc*16 + i;
            float v = src[(size_t)(bx*64 + r)*ld + scol + c];
            if (useg) v *= gamma[bx*64 + r];
            part += v;
            ts[r][c] = v;
        }
        __syncthreads();
#pragma unroll
        for (int i = 0; i < 16; ++i) {
            int r = rc*16 + i;
            dst[(size_t)(drow0 + r)*1024 + bx*64 + c] = (h16)ts[c][r];
        }
        if (useg) {
            __syncthreads();
            ts[rc][c] = part;
            __syncthreads();
            if (rc == 0) {
                float s = ts[0][c] + ts[1][c] + ts[2][c] + ts[3][c];
                cqp[(size_t)bx*1024 + scol + c] = s;
            }
        }
    } else if (pid < 1568) {
        int w = tid >> 6, l = tid & 63;
        int row = (pid - 544)*4 + w;
        const float* xr = x + (size_t)row*1024;
        float s = 0.f, ss = 0.f;
        float4 v[4];
#pragma unroll
        for (int i = 0; i < 4; ++i) {
            v[i] = *(const float4*)(xr + i*256 + l*4);
            s  += v[i].x + v[i].y + v[i].z + v[i].w;
            ss += v[i].x*v[i].x + v[i].y*v[i].y + v[i].z*v[i].z + v[i].w*v[i].w;
        }
#pragma unroll
        for (int m = 1; m < 64; m <<= 1) { s += __shfl_xor(s, m); ss += __shfl_xor(ss, m); }
        float m_ = s * (1.f/1024.f);
        float var = ss * (1.f/1024.f) - m_*m_;
        float r_ = rsqrtf(var + 1e-5f);
        if (l == 0) { mu[row] = m_; rr[row] = r_; }
        h16* xo = xh + (size_t)row*1024;
#pragma unroll
        for (int i = 0; i < 4; ++i) {
            f16x4 hv = { (h16)v[i].x, (h16)v[i].y, (h16)v[i].z, (h16)v[i].w };
            *(f16x4*)(xo + i*256 + l*4) = hv;
        }
    } else {
        int nb = pid - 1568;
        if (nb == 0 && tid < 128) {
            int t = tid >> 6, d = tid & 63;
            float kv = nkv[(0*2 + t)*64 + d];
            float ss = kv*kv;
#pragma unroll
            for (int m = 1; m < 64; m <<= 1) ss += __shfl_xor(ss, m);
            float inv = 1.f / fmaxf(sqrtf(ss), 1e-12f);
            h16 kvh = (h16)(kv * inv * kscale[d] * KSCALE_FOLD);
            Kh[(size_t)(0*2112 + t)*64 + d] = kvh;
            Kh[(size_t)(1*2112 + t)*64 + d] = kvh;
            float nv = nkv[(2 + t)*64 + d];
            Vth[(size_t)(0*64 + d)*2112 + t] = (h16)nv;
            Vth[(size_t)(1*64 + d)*2112 + t] = (h16)nv;
        }
        for (int idx = nb*256 + tid; idx < 2*62*64; idx += 2048) {
            int b = idx / (62*64), rem = idx % (62*64);
            int j = 2050 + rem/64, d = rem & 63;
            Kh[((size_t)b*2112 + j)*64 + d] = (h16)0.f;
            Vth[((size_t)b*64 + d)*2112 + j] = (h16)0.f;
        }
    }
}

// ---------------- GEMM (128x64 tile, BK=64, single-barrier dbuf gl_lds + XOR swizzle) ----------------
template<int MODE>
__global__ __launch_bounds__(256) void gemm_k(
    const h16* __restrict__ A, const h16* __restrict__ B,
    const float* __restrict__ mu, const float* __restrict__ rr, const float* __restrict__ cqp,
    const float* __restrict__ qscale, const float* __restrict__ kscale,
    h16* __restrict__ Qh, h16* __restrict__ Kh, h16* __restrict__ Vth, float* __restrict__ outp)
{
    __shared__ h16 As[2][128*64];   // 32KB
    __shared__ h16 Bs[2][64*64];    // 16KB
    int tid = threadIdx.x;
    int w = tid >> 6, l = tid & 63;
    int lq = l & 15, qq = l >> 4;
    int arow0 = blockIdx.y*128, bcol0 = blockIdx.x*64;
    const int K = 1024;
    f32x4 acc[2][4] = {};

    auto STAGE = [&](int buf, int kt) {
#pragma unroll
        for (int i = 0; i < 4; ++i) {            // A: 128x64 = 1024 slots
            int s = i*256 + tid;
            int row = s >> 3;
            int cb = ((s & 7)*16) ^ ((row & 7) << 4);
            const char* asrc = (const char*)(A + (size_t)(arow0 + row)*K + kt) + cb;
            __builtin_amdgcn_global_load_lds(
                (const __attribute__((address_space(1))) unsigned int*)asrc,
                (__attribute__((address_space(3))) unsigned int*)((char*)&As[buf][0] + s*16), 16, 0, 0);
        }
#pragma unroll
        for (int i = 0; i < 2; ++i) {            // B: 64x64 = 512 slots
            int s = i*256 + tid;
            int row = s >> 3;
            int cb = ((s & 7)*16) ^ ((row & 7) << 4);
            const char* bsrc = (const char*)(B + (size_t)(bcol0 + row)*K + kt) + cb;
            __builtin_amdgcn_global_load_lds(
                (const __attribute__((address_space(1))) unsigned int*)bsrc,
                (__attribute__((address_space(3))) unsigned int*)((char*)&Bs[buf][0] + s*16), 16, 0, 0);
        }
    };

    STAGE(0, 0);
    asm volatile("s_waitcnt vmcnt(0)" ::: "memory");
    __builtin_amdgcn_s_barrier();
    __builtin_amdgcn_sched_barrier(0);
    int cur = 0;
    for (int kt = 0; kt < K; kt += 64) {
        int nkt = (kt + 64 < K) ? kt + 64 : kt;
        STAGE(cur ^ 1, nkt);
        const char* Ab = (const char*)&As[cur][0];
        const char* Bb = (const char*)&Bs[cur][0];
#pragma unroll
        for (int kc = 0; kc < 2; ++kc) {
            int cb = (kc*64 + qq*16) ^ ((lq & 7) << 4);
            f16x8 af[2], bf[4];
#pragma unroll
            for (int mt = 0; mt < 2; ++mt)
                af[mt] = *(const f16x8*)(Ab + (w*32 + mt*16 + lq)*128 + cb);
#pragma unroll
            for (int nt = 0; nt < 4; ++nt)
                bf[nt] = *(const f16x8*)(Bb + (nt*16 + lq)*128 + cb);
#pragma unroll
            for (int mt = 0; mt < 2; ++mt)
#pragma unroll
                for (int nt = 0; nt < 4; ++nt)
                    acc[mt][nt] = __builtin_amdgcn_mfma_f32_16x16x32_f16(af[mt], bf[nt], acc[mt][nt], 0, 0, 0);
        }
        __builtin_amdgcn_sched_barrier(0);
        asm volatile("s_waitcnt vmcnt(0)" ::: "memory");
        __builtin_amdgcn_s_barrier();
        __builtin_amdgcn_sched_barrier(0);
        cur ^= 1;
    }

    int wrow0 = arow0 + w*32;
    int bx = blockIdx.x;
    if (MODE == 1) {
#pragma unroll
        for (int mt = 0; mt < 2; ++mt)
#pragma unroll
            for (int nt = 0; nt < 4; ++nt)
#pragma unroll
                for (int i = 0; i < 4; ++i)
                    outp[(size_t)(wrow0 + mt*16 + qq*4 + i)*1024 + bcol0 + nt*16 + lq] = acc[mt][nt][i];
        return;
    }
    if (bx < 16) {          // q columns: LN-fold + l2norm * q_scale (head = bx)
        float cqv[4], qs[4];
#pragma unroll
        for (int nt = 0; nt < 4; ++nt) {
            int col = bcol0 + nt*16 + lq;
            float s = 0.f;
#pragma unroll
            for (int j = 0; j < 16; ++j) s += cqp[(size_t)j*1024 + col];
            cqv[nt] = s;
            qs[nt] = qscale[nt*16 + lq];
        }
#pragma unroll
        for (int mt = 0; mt < 2; ++mt) {
            float muv[4], rv[4], ssq[4], qv[4][4];
#pragma unroll
            for (int i = 0; i < 4; ++i) {
                int row = wrow0 + mt*16 + qq*4 + i;
                muv[i] = mu[row]; rv[i] = rr[row]; ssq[i] = 0.f;
            }
#pragma unroll
            for (int nt = 0; nt < 4; ++nt)
#pragma unroll
                for (int i = 0; i < 4; ++i) {
                    float q = rv[i]*(acc[mt][nt][i] - muv[i]*cqv[nt]);
                    qv[nt][i] = q; ssq[i] += q*q;
                }
#pragma unroll
            for (int i = 0; i < 4; ++i) {
                float s2 = ssq[i];
                s2 += __shfl_xor(s2, 1); s2 += __shfl_xor(s2, 2);
                s2 += __shfl_xor(s2, 4); s2 += __shfl_xor(s2, 8);
                ssq[i] = 1.f / fmaxf(sqrtf(s2), 1e-12f);
            }
#pragma unroll
            for (int nt = 0; nt < 4; ++nt)
#pragma unroll
                for (int i = 0; i < 4; ++i) {
                    int row = wrow0 + mt*16 + qq*4 + i;
                    Qh[(size_t)row*1024 + bcol0 + nt*16 + lq] = (h16)(qv[nt][i]*ssq[i]*qs[nt]);
                }
        }
    } else if (bx == 16) {  // k: l2norm * k_scale * 8log2e
        float ks[4];
#pragma unroll
        for (int nt = 0; nt < 4; ++nt) ks[nt] = kscale[nt*16 + lq] * KSCALE_FOLD;
#pragma unroll
        for (int mt = 0; mt < 2; ++mt) {
            float ssq[4] = {0.f, 0.f, 0.f, 0.f};
#pragma unroll
            for (int nt = 0; nt < 4; ++nt)
#pragma unroll
                for (int i = 0; i < 4; ++i) ssq[i] += acc[mt][nt][i]*acc[mt][nt][i];
#pragma unroll
            for (int i = 0; i < 4; ++i) {
                float s2 = ssq[i];
                s2 += __shfl_xor(s2, 1); s2 += __shfl_xor(s2, 2);
                s2 += __shfl_xor(s2, 4); s2 += __shfl_xor(s2, 8);
                ssq[i] = 1.f / fmaxf(sqrtf(s2), 1e-12f);
            }
#pragma unroll
            for (int nt = 0; nt < 4; ++nt)
#pragma unroll
                for (int i = 0; i < 4; ++i) {
                    int row = wrow0 + mt*16 + qq*4 + i;
                    int b = row >> 11, ii = row & 2047;
                    Kh[((size_t)b*2112 + 2 + ii)*64 + nt*16 + lq] = (h16)(acc[mt][nt][i]*ssq[i]*ks[nt]);
                }
        }
    } else {                // v: transposed store
#pragma unroll
        for (int mt = 0; mt < 2; ++mt)
#pragma unroll
            for (int nt = 0; nt < 4; ++nt)
#pragma unroll
                for (int i = 0; i < 4; ++i) {
                    int row = wrow0 + mt*16 + qq*4 + i;
                    int b = row >> 11, ii = row & 2047;
                    Vth[((size_t)b*64 + nt*16 + lq)*2112 + 2 + ii] = (h16)acc[mt][nt][i];
                }
    }
}

// ---------------- attention: single-barrier dbuf + LDS-P + raw v_exp + MFMA row-sum ----------------
// block = 64 q rows (4 waves x 16 rows), K/V LDS-staged double-buffered.
__global__ __launch_bounds__(256, 4) void attn_k(const h16* __restrict__ Qh,
    const h16* __restrict__ Kh, const h16* __restrict__ Vth, h16* __restrict__ Oh)
{
    __shared__ h16 KVs[2][2][64*64];   // 32KB [buf][K|V] swizzled
    __shared__ h16 Ps[4][16*64];       // 8KB per-wave P (128B rows)
    int id = blockIdx.x;
    int u = id >> 5;
    int qt = (u < 16) ? u : 47 - u;
    int bh = id & 31;
    int b = bh >> 4, h = bh & 15;
    int tid = threadIdx.x, w = tid >> 6, l = tid & 63;
    int lq = l & 15, qq = l >> 4;
    int qstart = qt * 64;
    int q0w = qstart + w * 16;
    h16* P = &Ps[w][0];
    int xs = (lq & 7) << 4;

    f16x8 qf[2];
#pragma unroll
    for (int kc = 0; kc < 2; ++kc)
        qf[kc] = *(const f16x8*)(Qh + (size_t)(b*2048 + q0w + lq)*1024 + h*64 + kc*32 + qq*8);

    f16x8 ones;
#pragma unroll
    for (int i = 0; i < 8; ++i) ones[i] = (h16)1.f;

    int qrow = q0w + lq;
    int thr = (qrow < 64) ? 65 : qrow + 2;

    int cbs = ((tid & 7)*16) ^ (((tid >> 3) & 7) << 4);
    const char* ksrc = (const char*)(Kh + (size_t)b*2112*64) + (size_t)(tid >> 3)*128 + cbs;
    const char* vsrc = (const char*)(Vth + (size_t)b*64*2112) + (size_t)(tid >> 3)*4224 + cbs;

    f32x4 oacc[4] = {};
    f32x4 sacc = {};   // ones-MFMA accumulator: every element = sum_kv P[kv][lq]

    int lastc = qstart + 65;
    if (lastc > 2049) lastc = 2049;
    int ntile = lastc/64 + 1;

    auto STAGE = [&](int buf, int kv0) {
        const char* ks = ksrc + (size_t)kv0 * 128;
        const char* vs = vsrc + (size_t)kv0 * 2;
        __builtin_amdgcn_global_load_lds((const __attribute__((address_space(1))) unsigned int*)ks,
            (__attribute__((address_space(3))) unsigned int*)(&KVs[buf][0][(w*8)*64]), 16, 0, 0);
        __builtin_amdgcn_global_load_lds((const __attribute__((address_space(1))) unsigned int*)(ks + 32*128),
            (__attribute__((address_space(3))) unsigned int*)(&KVs[buf][0][(32 + w*8)*64]), 16, 0, 0);
        __builtin_amdgcn_global_load_lds((const __attribute__((address_space(1))) unsigned int*)vs,
            (__attribute__((address_space(3))) unsigned int*)(&KVs[buf][1][(w*8)*64]), 16, 0, 0);
        __builtin_amdgcn_global_load_lds((const __attribute__((address_space(1))) unsigned int*)(vs + (size_t)32*4224),
            (__attribute__((address_space(3))) unsigned int*)(&KVs[buf][1][(32 + w*8)*64]), 16, 0, 0);
    };

    STAGE(0, 0);
    asm volatile("s_waitcnt vmcnt(0)" ::: "memory");
    __builtin_amdgcn_s_barrier();
    __builtin_amdgcn_sched_barrier(0);
    int cur = 0;
    for (int t = 0; t < ntile; ++t) {
        int kv0 = t*64;
        int nxt = (t + 1 < ntile) ? t + 1 : t;
        STAGE(cur ^ 1, nxt*64);

        bool active = (kv0 <= q0w + 17) || (q0w < 64 && kv0 < 66);
        if (active) {
            const char* Kl = (const char*)&KVs[cur][0][0];
            const char* Vl = (const char*)&KVs[cur][1][0];
            f32x4 s[4] = {};
            __builtin_amdgcn_s_setprio(1);
#pragma unroll
            for (int kc = 0; kc < 2; ++kc) {
                int ko = (kc*64 + qq*16) ^ xs;
                f16x8 kf[4];
#pragma unroll
                for (int mt = 0; mt < 4; ++mt)
                    kf[mt] = *(const f16x8*)(Kl + (mt*16 + lq)*128 + ko);
#pragma unroll
                for (int mt = 0; mt < 4; ++mt)
                    s[mt] = __builtin_amdgcn_mfma_f32_16x16x32_f16(kf[mt], qf[kc], s[mt], 0, 0, 0);
            }
            __builtin_amdgcn_s_setprio(0);
            if (kv0 + 63 > q0w + 2) {   // mask needed
#pragma unroll
                for (int mt = 0; mt < 4; ++mt)
#pragma unroll
                    for (int i = 0; i < 4; ++i) {
                        int kv = kv0 + mt*16 + qq*4 + i;
                        if (kv > thr) s[mt][i] = -__builtin_inff();
                    }
            }
#pragma unroll
            for (int mt = 0; mt < 4; ++mt)
#pragma unroll
                for (int i = 0; i < 4; ++i)
                    s[mt][i] = EXP2(s[mt][i]);
#pragma unroll
            for (int mt = 0; mt < 4; ++mt) {
                uint2 pk;
                pk.x = __builtin_bit_cast(unsigned int, __builtin_amdgcn_cvt_pkrtz(s[mt][0], s[mt][1]));
                pk.y = __builtin_bit_cast(unsigned int, __builtin_amdgcn_cvt_pkrtz(s[mt][2], s[mt][3]));
                *(uint2*)((char*)P + lq*128 + ((mt*32 + qq*8) ^ xs)) = pk;
            }
            __builtin_amdgcn_s_setprio(1);
#pragma unroll
            for (int kc = 0; kc < 2; ++kc) {
                int ko = (kc*64 + qq*16) ^ xs;
                f16x8 pf = *(const f16x8*)((const char*)P + lq*128 + ko);
#pragma unroll
                for (int dm = 0; dm < 4; ++dm) {
                    f16x8 vf = *(const f16x8*)(Vl + (dm*16 + lq)*128 + ko);
                    oacc[dm] = __builtin_amdgcn_mfma_f32_16x16x32_f16(vf, pf, oacc[dm], 0, 0, 0);
                }
                sacc = __builtin_amdgcn_mfma_f32_16x16x32_f16(ones, pf, sacc, 0, 0, 0);
            }
            __builtin_amdgcn_s_setprio(0);
        }
        __builtin_amdgcn_sched_barrier(0);
        asm volatile("s_waitcnt vmcnt(0)" ::: "memory");
        __builtin_amdgcn_s_barrier();
        __builtin_amdgcn_sched_barrier(0);
        cur ^= 1;
    }

    float inv = 1.f / sacc[0];
#pragma unroll
    for (int dm = 0; dm < 4; ++dm) {
        f16x4 ov;
#pragma unroll
        for (int i = 0; i < 4; ++i) ov[i] = (h16)(oacc[dm][i]*inv);
        *(f16x4*)(Oh + (size_t)(b*2048 + q0w + lq)*1024 + h*64 + dm*16 + qq*4) = ov;
    }
}

extern "C" void kernel_launch(void* const* d_in, const int* in_sizes, int n_in,
                              void* d_out, int out_size, void* d_ws, size_t ws_size,
                              hipStream_t stream)
{
    const float* x      = (const float*)d_in[0];
    const float* gamma  = (const float*)d_in[1];
    const float* Wq     = (const float*)d_in[2];
    const float* Wkv    = (const float*)d_in[3];
    const float* qscale = (const float*)d_in[4];
    const float* kscale = (const float*)d_in[5];
    const float* nkv    = (const float*)d_in[6];
    const float* Wout   = (const float*)d_in[7];
    float* out = (float*)d_out;
    char* ws = (char*)d_ws;

    h16* xh    = (h16*)(ws);                     // 8388608
    h16* Qh    = (h16*)(ws + 8388608);           // 8388608
    h16* Oh    = (h16*)(ws + 16777216);          // 8388608
    h16* W1t   = (h16*)(ws + 25165824);          // 2359296
    h16* Wot   = (h16*)(ws + 27525120);          // 2097152
    h16* Kh    = (h16*)(ws + 29622272);          // 540672
    h16* Vth   = (h16*)(ws + 30162944);          // 540672
    float* cqp = (float*)(ws + 30703616);        // 65536
    float* mu  = (float*)(ws + 30769152);        // 16384
    float* rr  = (float*)(ws + 30785536);        // 16384

    pre_k<<<dim3(1576), 256, 0, stream>>>(Wq, Wkv, Wout, gamma, x, nkv, kscale,
                                          W1t, Wot, cqp, mu, rr, xh, Kh, Vth);
    gemm_k<0><<<dim3(18, 32), 256, 0, stream>>>(xh, W1t, mu, rr, cqp, qscale, kscale, Qh, Kh, Vth, out);
    attn_k<<<dim3(1024), 256, 0, stream>>>(Qh, Kh, Vth, Oh);
    gemm_k<1><<<dim3(16, 32), 256, 0, stream>>>(Oh, Wot, mu, rr, cqp, qscale, kscale, Qh, Kh, Vth, out);
}

// Round 17
// 85.971 us; speedup vs baseline: 1.0529x; 1.0529x over previous
//
#include <hip/hip_runtime.h>

typedef _Float16 h16;
typedef _Float16 f16x8 __attribute__((ext_vector_type(8)));
typedef _Float16 f16x4 __attribute__((ext_vector_type(4)));
typedef float f32x4 __attribute__((ext_vector_type(4)));

#define KSCALE_FOLD 11.541560327111707f   // 8 * log2(e), folded into Kh

#if __has_builtin(__builtin_amdgcn_exp2f)
#define EXP2(x) __builtin_amdgcn_exp2f(x)
#else
static __device__ __forceinline__ float EXP2(float x) {
    float r; asm("v_exp_f32 %0, %1" : "=v"(r) : "v"(x)); return r;
}
#endif

// ---------------- fused pre-pass: weight transposes + x stats/convert + null kv ----------------
// cq partials: block (bx, by<16) writes cqp[bx][by*64+c] (no atomics, no zero-init).
__global__ __launch_bounds__(256) void pre_k(const float* __restrict__ Wq,
    const float* __restrict__ Wkv, const float* __restrict__ Wout,
    const float* __restrict__ gamma, const float* __restrict__ x,
    const float* __restrict__ nkv, const float* __restrict__ kscale,
    h16* __restrict__ W1t, h16* __restrict__ Wot, float* __restrict__ cqp,
    float* __restrict__ mu, float* __restrict__ rr, h16* __restrict__ xh,
    h16* __restrict__ Kh, h16* __restrict__ Vth)
{
    __shared__ float ts[64][65];
    int pid = blockIdx.x;
    int tid = threadIdx.x;
    if (pid < 544) {
        int bx = pid & 15, by = pid >> 4;
        int c = tid & 63, rc = tid >> 6;
        const float* src; int ld, scol, drow0; h16* dst; bool useg = false;
        if (by < 16)      { src = Wq;   ld = 1024; scol = by*64;       dst = W1t; drow0 = scol;        useg = true; }
        else if (by < 18) { src = Wkv;  ld = 128;  scol = (by-16)*64;  dst = W1t; drow0 = 1024 + scol; }
        else              { src = Wout; ld = 1024; scol = (by-18)*64;  dst = Wot; drow0 = scol; }
        float part = 0.f;
#pragma unroll
        for (int i = 0; i < 16; ++i) {
            int r = rc*16 + i;
            float v = src[(size_t)(bx*64 + r)*ld + scol + c];
            if (useg) v *= gamma[bx*64 + r];
            part += v;
            ts[r][c] = v;
        }
        __syncthreads();
#pragma unroll
        for (int i = 0; i < 16; ++i) {
            int r = rc*16 + i;
            dst[(size_t)(drow0 + r)*1024 + bx*64 + c] = (h16)ts[c][r];
        }
        if (useg) {
            __syncthreads();
            ts[rc][c] = part;
            __syncthreads();
            if (rc == 0) {
                float s = ts[0][c] + ts[1][c] + ts[2][c] + ts[3][c];
                cqp[(size_t)bx*1024 + scol + c] = s;
            }
        }
    } else if (pid < 1568) {
        int w = tid >> 6, l = tid & 63;
        int row = (pid - 544)*4 + w;
        const float* xr = x + (size_t)row*1024;
        float s = 0.f, ss = 0.f;
        float4 v[4];
#pragma unroll
        for (int i = 0; i < 4; ++i) {
            v[i] = *(const float4*)(xr + i*256 + l*4);
            s  += v[i].x + v[i].y + v[i].z + v[i].w;
            ss += v[i].x*v[i].x + v[i].y*v[i].y + v[i].z*v[i].z + v[i].w*v[i].w;
        }
#pragma unroll
        for (int m = 1; m < 64; m <<= 1) { s += __shfl_xor(s, m); ss += __shfl_xor(ss, m); }
        float m_ = s * (1.f/1024.f);
        float var = ss * (1.f/1024.f) - m_*m_;
        float r_ = rsqrtf(var + 1e-5f);
        if (l == 0) { mu[row] = m_; rr[row] = r_; }
        h16* xo = xh + (size_t)row*1024;
#pragma unroll
        for (int i = 0; i < 4; ++i) {
            f16x4 hv = { (h16)v[i].x, (h16)v[i].y, (h16)v[i].z, (h16)v[i].w };
            *(f16x4*)(xo + i*256 + l*4) = hv;
        }
    } else {
        int nb = pid - 1568;
        if (nb == 0 && tid < 128) {
            int t = tid >> 6, d = tid & 63;
            float kv = nkv[(0*2 + t)*64 + d];
            float ss = kv*kv;
#pragma unroll
            for (int m = 1; m < 64; m <<= 1) ss += __shfl_xor(ss, m);
            float inv = 1.f / fmaxf(sqrtf(ss), 1e-12f);
            h16 kvh = (h16)(kv * inv * kscale[d] * KSCALE_FOLD);
            Kh[(size_t)(0*2112 + t)*64 + d] = kvh;
            Kh[(size_t)(1*2112 + t)*64 + d] = kvh;
            float nv = nkv[(2 + t)*64 + d];
            Vth[(size_t)(0*64 + d)*2112 + t] = (h16)nv;
            Vth[(size_t)(1*64 + d)*2112 + t] = (h16)nv;
        }
        for (int idx = nb*256 + tid; idx < 2*62*64; idx += 2048) {
            int b = idx / (62*64), rem = idx % (62*64);
            int j = 2050 + rem/64, d = rem & 63;
            Kh[((size_t)b*2112 + j)*64 + d] = (h16)0.f;
            Vth[((size_t)b*64 + d)*2112 + j] = (h16)0.f;
        }
    }
}

// ---------------- GEMM (128x64 tile, BK=64, 4 waves M-stacked, dbuf gl_lds + XOR swizzle) ----------------
template<int MODE>
__global__ __launch_bounds__(256) void gemm_k(
    const h16* __restrict__ A, const h16* __restrict__ B,
    const float* __restrict__ mu, const float* __restrict__ rr, const float* __restrict__ cqp,
    const float* __restrict__ qscale, const float* __restrict__ kscale,
    h16* __restrict__ Qh, h16* __restrict__ Kh, h16* __restrict__ Vth, float* __restrict__ outp)
{
    __shared__ h16 As[2][128*64];   // 32KB
    __shared__ h16 Bs[2][64*64];    // 16KB
    int tid = threadIdx.x;
    int w = tid >> 6, l = tid & 63;
    int lq = l & 15, qq = l >> 4;
    int arow0 = blockIdx.y*128, bcol0 = blockIdx.x*64;
    const int K = 1024;
    f32x4 acc[2][4] = {};

    auto STAGE = [&](int buf, int kt) {
#pragma unroll
        for (int i = 0; i < 4; ++i) {            // A: 128x64 = 1024 slots
            int s = i*256 + tid;
            int row = s >> 3;
            int cb = ((s & 7)*16) ^ ((row & 7) << 4);
            const char* asrc = (const char*)(A + (size_t)(arow0 + row)*K + kt) + cb;
            __builtin_amdgcn_global_load_lds(
                (const __attribute__((address_space(1))) unsigned int*)asrc,
                (__attribute__((address_space(3))) unsigned int*)((char*)&As[buf][0] + s*16), 16, 0, 0);
        }
#pragma unroll
        for (int i = 0; i < 2; ++i) {            // B: 64x64 = 512 slots
            int s = i*256 + tid;
            int row = s >> 3;
            int cb = ((s & 7)*16) ^ ((row & 7) << 4);
            const char* bsrc = (const char*)(B + (size_t)(bcol0 + row)*K + kt) + cb;
            __builtin_amdgcn_global_load_lds(
                (const __attribute__((address_space(1))) unsigned int*)bsrc,
                (__attribute__((address_space(3))) unsigned int*)((char*)&Bs[buf][0] + s*16), 16, 0, 0);
        }
    };

    STAGE(0, 0);
    int cur = 0;
    for (int kt = 0; kt < K; kt += 64) {
        int nkt = (kt + 64 < K) ? kt + 64 : kt;
        STAGE(cur ^ 1, nkt);
        asm volatile("s_waitcnt vmcnt(6)" ::: "memory");
        __builtin_amdgcn_s_barrier();
        __builtin_amdgcn_sched_barrier(0);
        const char* Ab = (const char*)&As[cur][0];
        const char* Bb = (const char*)&Bs[cur][0];
#pragma unroll
        for (int kc = 0; kc < 2; ++kc) {
            int cb = (kc*64 + qq*16) ^ ((lq & 7) << 4);
            f16x8 af[2], bf[4];
#pragma unroll
            for (int mt = 0; mt < 2; ++mt)
                af[mt] = *(const f16x8*)(Ab + (w*32 + mt*16 + lq)*128 + cb);
#pragma unroll
            for (int nt = 0; nt < 4; ++nt)
                bf[nt] = *(const f16x8*)(Bb + (nt*16 + lq)*128 + cb);
#pragma unroll
            for (int mt = 0; mt < 2; ++mt)
#pragma unroll
                for (int nt = 0; nt < 4; ++nt)
                    acc[mt][nt] = __builtin_amdgcn_mfma_f32_16x16x32_f16(af[mt], bf[nt], acc[mt][nt], 0, 0, 0);
        }
        __builtin_amdgcn_sched_barrier(0);
        __builtin_amdgcn_s_barrier();
        cur ^= 1;
    }
    asm volatile("s_waitcnt vmcnt(0)" ::: "memory");

    int wrow0 = arow0 + w*32;
    int bx = blockIdx.x;
    if (MODE == 1) {
#pragma unroll
        for (int mt = 0; mt < 2; ++mt)
#pragma unroll
            for (int nt = 0; nt < 4; ++nt)
#pragma unroll
                for (int i = 0; i < 4; ++i)
                    outp[(size_t)(wrow0 + mt*16 + qq*4 + i)*1024 + bcol0 + nt*16 + lq] = acc[mt][nt][i];
        return;
    }
    if (bx < 16) {          // q columns: LN-fold + l2norm * q_scale (head = bx)
        float cqv[4], qs[4];
#pragma unroll
        for (int nt = 0; nt < 4; ++nt) {
            int col = bcol0 + nt*16 + lq;
            float s = 0.f;
#pragma unroll
            for (int j = 0; j < 16; ++j) s += cqp[(size_t)j*1024 + col];
            cqv[nt] = s;
            qs[nt] = qscale[nt*16 + lq];
        }
#pragma unroll
        for (int mt = 0; mt < 2; ++mt) {
            float muv[4], rv[4], ssq[4], qv[4][4];
#pragma unroll
            for (int i = 0; i < 4; ++i) {
                int row = wrow0 + mt*16 + qq*4 + i;
                muv[i] = mu[row]; rv[i] = rr[row]; ssq[i] = 0.f;
            }
#pragma unroll
            for (int nt = 0; nt < 4; ++nt)
#pragma unroll
                for (int i = 0; i < 4; ++i) {
                    float q = rv[i]*(acc[mt][nt][i] - muv[i]*cqv[nt]);
                    qv[nt][i] = q; ssq[i] += q*q;
                }
#pragma unroll
            for (int i = 0; i < 4; ++i) {
                float s2 = ssq[i];
                s2 += __shfl_xor(s2, 1); s2 += __shfl_xor(s2, 2);
                s2 += __shfl_xor(s2, 4); s2 += __shfl_xor(s2, 8);
                ssq[i] = 1.f / fmaxf(sqrtf(s2), 1e-12f);
            }
#pragma unroll
            for (int nt = 0; nt < 4; ++nt)
#pragma unroll
                for (int i = 0; i < 4; ++i) {
                    int row = wrow0 + mt*16 + qq*4 + i;
                    Qh[(size_t)row*1024 + bcol0 + nt*16 + lq] = (h16)(qv[nt][i]*ssq[i]*qs[nt]);
                }
        }
    } else if (bx == 16) {  // k: l2norm * k_scale * 8log2e
        float ks[4];
#pragma unroll
        for (int nt = 0; nt < 4; ++nt) ks[nt] = kscale[nt*16 + lq] * KSCALE_FOLD;
#pragma unroll
        for (int mt = 0; mt < 2; ++mt) {
            float ssq[4] = {0.f, 0.f, 0.f, 0.f};
#pragma unroll
            for (int nt = 0; nt < 4; ++nt)
#pragma unroll
                for (int i = 0; i < 4; ++i) ssq[i] += acc[mt][nt][i]*acc[mt][nt][i];
#pragma unroll
            for (int i = 0; i < 4; ++i) {
                float s2 = ssq[i];
                s2 += __shfl_xor(s2, 1); s2 += __shfl_xor(s2, 2);
                s2 += __shfl_xor(s2, 4); s2 += __shfl_xor(s2, 8);
                ssq[i] = 1.f / fmaxf(sqrtf(s2), 1e-12f);
            }
#pragma unroll
            for (int nt = 0; nt < 4; ++nt)
#pragma unroll
                for (int i = 0; i < 4; ++i) {
                    int row = wrow0 + mt*16 + qq*4 + i;
                    int b = row >> 11, ii = row & 2047;
                    Kh[((size_t)b*2112 + 2 + ii)*64 + nt*16 + lq] = (h16)(acc[mt][nt][i]*ssq[i]*ks[nt]);
                }
        }
    } else {                // v: transposed store
#pragma unroll
        for (int mt = 0; mt < 2; ++mt)
#pragma unroll
            for (int nt = 0; nt < 4; ++nt)
#pragma unroll
                for (int i = 0; i < 4; ++i) {
                    int row = wrow0 + mt*16 + qq*4 + i;
                    int b = row >> 11, ii = row & 2047;
                    Vth[((size_t)b*64 + nt*16 + lq)*2112 + 2 + ii] = (h16)acc[mt][nt][i];
                }
    }
}

// ---------------- attention: LDS-staged dbuf + raw v_exp + MFMA row-sum ----------------
__global__ __launch_bounds__(256, 4) void attn_k(const h16* __restrict__ Qh,
    const h16* __restrict__ Kh, const h16* __restrict__ Vth, h16* __restrict__ Oh)
{
    __shared__ h16 KVs[2][2][64*64];   // 32KB [buf][K|V] swizzled
    __shared__ h16 Ps[4][16*64];       // 8KB per-wave P (128B rows)
    int id = blockIdx.x;
    int u = id >> 5;
    int qt = (u < 16) ? u : 47 - u;
    int bh = id & 31;
    int b = bh >> 4, h = bh & 15;
    int tid = threadIdx.x, w = tid >> 6, l = tid & 63;
    int lq = l & 15, qq = l >> 4;
    int qstart = qt * 64;
    int q0w = qstart + w * 16;
    h16* P = &Ps[w][0];
    int xs = (lq & 7) << 4;

    f16x8 qf[2];
#pragma unroll
    for (int kc = 0; kc < 2; ++kc)
        qf[kc] = *(const f16x8*)(Qh + (size_t)(b*2048 + q0w + lq)*1024 + h*64 + kc*32 + qq*8);

    f16x8 ones;
#pragma unroll
    for (int i = 0; i < 8; ++i) ones[i] = (h16)1.f;

    int qrow = q0w + lq;
    int thr = (qrow < 64) ? 65 : qrow + 2;

    int cbs = ((tid & 7)*16) ^ (((tid >> 3) & 7) << 4);
    const char* ksrc = (const char*)(Kh + (size_t)b*2112*64) + (size_t)(tid >> 3)*128 + cbs;
    const char* vsrc = (const char*)(Vth + (size_t)b*64*2112) + (size_t)(tid >> 3)*4224 + cbs;

    f32x4 oacc[4] = {};
    f32x4 sacc = {};   // ones-MFMA accumulator: every element = sum_kv P[kv][lq]

    int lastc = qstart + 65;
    if (lastc > 2049) lastc = 2049;
    int ntile = lastc/64 + 1;

    auto STAGE = [&](int buf, int kv0) {
        const char* ks = ksrc + (size_t)kv0 * 128;
        const char* vs = vsrc + (size_t)kv0 * 2;
        __builtin_amdgcn_global_load_lds((const __attribute__((address_space(1))) unsigned int*)ks,
            (__attribute__((address_space(3))) unsigned int*)(&KVs[buf][0][(w*8)*64]), 16, 0, 0);
        __builtin_amdgcn_global_load_lds((const __attribute__((address_space(1))) unsigned int*)(ks + 32*128),
            (__attribute__((address_space(3))) unsigned int*)(&KVs[buf][0][(32 + w*8)*64]), 16, 0, 0);
        __builtin_amdgcn_global_load_lds((const __attribute__((address_space(1))) unsigned int*)vs,
            (__attribute__((address_space(3))) unsigned int*)(&KVs[buf][1][(w*8)*64]), 16, 0, 0);
        __builtin_amdgcn_global_load_lds((const __attribute__((address_space(1))) unsigned int*)(vs + (size_t)32*4224),
            (__attribute__((address_space(3))) unsigned int*)(&KVs[buf][1][(32 + w*8)*64]), 16, 0, 0);
    };

    STAGE(0, 0);
    int cur = 0;
    for (int t = 0; t < ntile; ++t) {
        int kv0 = t*64;
        int nxt = (t + 1 < ntile) ? t + 1 : t;
        STAGE(cur ^ 1, nxt*64);
        asm volatile("s_waitcnt vmcnt(4)" ::: "memory");
        __builtin_amdgcn_s_barrier();
        __builtin_amdgcn_sched_barrier(0);

        bool active = (kv0 <= q0w + 17) || (q0w < 64 && kv0 < 66);
        if (active) {
            const char* Kl = (const char*)&KVs[cur][0][0];
            const char* Vl = (const char*)&KVs[cur][1][0];
            f32x4 s[4] = {};
#pragma unroll
            for (int kc = 0; kc < 2; ++kc) {
                int ko = (kc*64 + qq*16) ^ xs;
                f16x8 kf[4];
#pragma unroll
                for (int mt = 0; mt < 4; ++mt)
                    kf[mt] = *(const f16x8*)(Kl + (mt*16 + lq)*128 + ko);
#pragma unroll
                for (int mt = 0; mt < 4; ++mt)
                    s[mt] = __builtin_amdgcn_mfma_f32_16x16x32_f16(kf[mt], qf[kc], s[mt], 0, 0, 0);
            }
            if (kv0 + 63 > q0w + 2) {   // mask needed
#pragma unroll
                for (int mt = 0; mt < 4; ++mt)
#pragma unroll
                    for (int i = 0; i < 4; ++i) {
                        int kv = kv0 + mt*16 + qq*4 + i;
                        if (kv > thr) s[mt][i] = -__builtin_inff();
                    }
            }
#pragma unroll
            for (int mt = 0; mt < 4; ++mt)
#pragma unroll
                for (int i = 0; i < 4; ++i)
                    s[mt][i] = EXP2(s[mt][i]);
#pragma unroll
            for (int mt = 0; mt < 4; ++mt) {
                uint2 pk;
                pk.x = __builtin_bit_cast(unsigned int, __builtin_amdgcn_cvt_pkrtz(s[mt][0], s[mt][1]));
                pk.y = __builtin_bit_cast(unsigned int, __builtin_amdgcn_cvt_pkrtz(s[mt][2], s[mt][3]));
                *(uint2*)((char*)P + lq*128 + ((mt*32 + qq*8) ^ xs)) = pk;
            }
#pragma unroll
            for (int kc = 0; kc < 2; ++kc) {
                int ko = (kc*64 + qq*16) ^ xs;
                f16x8 pf = *(const f16x8*)((const char*)P + lq*128 + ko);
#pragma unroll
                for (int dm = 0; dm < 4; ++dm) {
                    f16x8 vf = *(const f16x8*)(Vl + (dm*16 + lq)*128 + ko);
                    oacc[dm] = __builtin_amdgcn_mfma_f32_16x16x32_f16(vf, pf, oacc[dm], 0, 0, 0);
                }
                sacc = __builtin_amdgcn_mfma_f32_16x16x32_f16(ones, pf, sacc, 0, 0, 0);
            }
        }
        __builtin_amdgcn_sched_barrier(0);
        __builtin_amdgcn_s_barrier();
        cur ^= 1;
    }
    asm volatile("s_waitcnt vmcnt(0)" ::: "memory");

    float inv = 1.f / sacc[0];
#pragma unroll
    for (int dm = 0; dm < 4; ++dm) {
        f16x4 ov;
#pragma unroll
        for (int i = 0; i < 4; ++i) ov[i] = (h16)(oacc[dm][i]*inv);
        *(f16x4*)(Oh + (size_t)(b*2048 + q0w + lq)*1024 + h*64 + dm*16 + qq*4) = ov;
    }
}

extern "C" void kernel_launch(void* const* d_in, const int* in_sizes, int n_in,
                              void* d_out, int out_size, void* d_ws, size_t ws_size,
                              hipStream_t stream)
{
    const float* x      = (const float*)d_in[0];
    const float* gamma  = (const float*)d_in[1];
    const float* Wq     = (const float*)d_in[2];
    const float* Wkv    = (const float*)d_in[3];
    const float* qscale = (const float*)d_in[4];
    const float* kscale = (const float*)d_in[5];
    const float* nkv    = (const float*)d_in[6];
    const float* Wout   = (const float*)d_in[7];
    float* out = (float*)d_out;
    char* ws = (char*)d_ws;

    h16* xh    = (h16*)(ws);                     // 8388608
    h16* Qh    = (h16*)(ws + 8388608);           // 8388608
    h16* Oh    = (h16*)(ws + 16777216);          // 8388608
    h16* W1t   = (h16*)(ws + 25165824);          // 2359296
    h16* Wot   = (h16*)(ws + 27525120);          // 2097152
    h16* Kh    = (h16*)(ws + 29622272);          // 540672
    h16* Vth   = (h16*)(ws + 30162944);          // 540672
    float* cqp = (float*)(ws + 30703616);        // 65536
    float* mu  = (float*)(ws + 30769152);        // 16384
    float* rr  = (float*)(ws + 30785536);        // 16384

    pre_k<<<dim3(1576), 256, 0, stream>>>(Wq, Wkv, Wout, gamma, x, nkv, kscale,
                                          W1t, Wot, cqp, mu, rr, xh, Kh, Vth);
    gemm_k<0><<<dim3(18, 32), 256, 0, stream>>>(xh, W1t, mu, rr, cqp, qscale, kscale, Qh, Kh, Vth, out);
    attn_k<<<dim3(1024), 256, 0, stream>>>(Qh, Kh, Vth, Oh);
    gemm_k<1><<<dim3(16, 32), 256, 0, stream>>>(Oh, Wot, mu, rr, cqp, qscale, kscale, Qh, Kh, Vth, out);
}